// Round 10
// baseline (384.616 us; speedup 1.0000x reference)
//
#include <hip/hip_runtime.h>
#include <hip/hip_bf16.h>
#include <stdint.h>

typedef unsigned long long u64;
typedef unsigned int u32;
typedef __attribute__((ext_vector_type(8))) short bf16x8;
typedef __attribute__((ext_vector_type(8))) unsigned short u16x8;
typedef __attribute__((ext_vector_type(4))) float f32x4;

__device__ __forceinline__ float ldv(const void* p, size_t idx, int mode) {
  return mode ? __bfloat162float(((const __hip_bfloat16*)p)[idx])
              : ((const float*)p)[idx];
}
__device__ __forceinline__ void stv(void* p, size_t idx, int mode, float v) {
  if (mode) ((__hip_bfloat16*)p)[idx] = __float2bfloat16(v);
  else      ((float*)p)[idx] = v;
}
__device__ __forceinline__ unsigned short f2bfb(float f) {  // RNE f32->bf16 bits
  u32 u = __float_as_uint(f);
  u32 r = u + 0x7fffu + ((u >> 16) & 1u);
  return (unsigned short)(r >> 16);
}
__device__ __forceinline__ float bfb2f(unsigned short b) {
  return __uint_as_float((u32)b << 16);
}
__device__ __forceinline__ u64 shfl64(u64 v, int src) {
  int lo = __shfl((int)(u32)(v & 0xffffffffu), src, 64);
  int hi = __shfl((int)(u32)(v >> 32), src, 64);
  return ((u64)(u32)hi << 32) | (u32)lo;
}
__device__ __forceinline__ u64 shflxor64(u64 v, int m) {
  int lo = __shfl_xor((int)(u32)(v & 0xffffffffu), m, 64);
  int hi = __shfl_xor((int)(u32)(v >> 32), m, 64);
  return ((u64)(u32)hi << 32) | (u32)lo;
}
__device__ __forceinline__ u64 shfl64w16(u64 v, int src) {  // width-16 shfl
  int lo = __shfl((int)(u32)(v & 0xffffffffu), src, 16);
  int hi = __shfl((int)(u32)(v >> 32), src, 16);
  return ((u64)(u32)hi << 32) | (u32)lo;
}

// monotonic float<->uint encoding for atomicMin-based bbox.
// Max is stored as benc(-x) so BOTH min and max slots init to 0xFF and use
// atomicMin; decode max = -bdec(slot). Negation is exact -> identical grid.
__device__ __forceinline__ u32 benc(float f) {
  u32 u = __float_as_uint(f);
  return (u & 0x80000000u) ? ~u : (u | 0x80000000u);
}
__device__ __forceinline__ float bdec(u32 k) {
  return (k & 0x80000000u) ? __uint_as_float(k ^ 0x80000000u)
                           : __uint_as_float(~k);
}

__global__ void PointNetSimple_61409442398998_kernel() {}

// ---------------------------------------------------------------------------
// setup: dtype-detect + weight transpose/convert + vector cvt + prep +
// bbox atomics + counts zeroing (fused).
// ---------------------------------------------------------------------------
struct CvtEnt { const void* src; float* dst; int n; };
struct CvtArgs { CvtEnt e[12]; };
struct WEnt { const void* src; unsigned short* dst; int K, N, Kpad; };
struct WArgs { WEnt e[6]; };

#define GR 32
#define GR3 (GR*GR*GR)

__global__ void setup_kernel(const void* __restrict__ pos,
                             const void* __restrict__ nrm,
                             WArgs wa, CvtArgs ca,
                             int* __restrict__ flag,
                             float4* __restrict__ pos4,
                             float* __restrict__ h0,
                             int* __restrict__ counts, int n) {
  const unsigned short* u16p = (const unsigned short*)pos;
  int cnt = 0;
  for (int k = 0; k < 32; ++k) {
    int e = (u16p[k] >> 7) & 0xff;
    if (e >= 110 && e <= 140) cnt++;
  }
  const int mode = (cnt >= 26) ? 1 : 0;

  const int nprep = n >> 8;
  const int b = blockIdx.x;
  if (b < nprep) {
    int i = b * 256 + threadIdx.x;
    float x = ldv(pos, 3*(size_t)i+0, mode);
    float y = ldv(pos, 3*(size_t)i+1, mode);
    float z = ldv(pos, 3*(size_t)i+2, mode);
    pos4[i] = make_float4(x, y, z, x*x + y*y + z*z);
    h0[6*(size_t)i+0] = x; h0[6*(size_t)i+1] = y; h0[6*(size_t)i+2] = z;
    h0[6*(size_t)i+3] = ldv(nrm, 3*(size_t)i+0, mode);
    h0[6*(size_t)i+4] = ldv(nrm, 3*(size_t)i+1, mode);
    h0[6*(size_t)i+5] = ldv(nrm, 3*(size_t)i+2, mode);
    // bbox contribution (bbx = ((u32*)flag)+4..9, all init'd to 0xFF)
    float bmn[3] = {x, y, z}, bmx[3] = {x, y, z};
#pragma unroll
    for (int m = 32; m; m >>= 1) {
#pragma unroll
      for (int k = 0; k < 3; ++k) {
        bmn[k] = fminf(bmn[k], __shfl_xor(bmn[k], m, 64));
        bmx[k] = fmaxf(bmx[k], __shfl_xor(bmx[k], m, 64));
      }
    }
    if ((threadIdx.x & 63) == 0) {
      u32* bb = (u32*)flag;
#pragma unroll
      for (int k = 0; k < 3; ++k) {
        atomicMin(&bb[4 + k], benc(bmn[k]));
        atomicMin(&bb[7 + k], benc(-bmx[k]));   // max via negated-min
      }
    }
  } else {
    int r = b - nprep;
    if (r < 6) {
      WEnt ent = wa.e[r];
      for (int t = threadIdx.x; t < ent.N * ent.Kpad; t += blockDim.x) {
        int nn = t / ent.Kpad;
        int k  = t - nn * ent.Kpad;
        float v = (k < ent.K) ? ldv(ent.src, (size_t)k * ent.N + nn, mode) : 0.0f;
        ent.dst[t] = f2bfb(v);
      }
      if (r == 0 && threadIdx.x == 0) flag[0] = mode;
    } else if (r == 6) {
      for (int t2 = 0; t2 < 12; ++t2) {
        CvtEnt ent = ca.e[t2];
        for (int t = threadIdx.x; t < ent.n; t += blockDim.x)
          ent.dst[t] = ldv(ent.src, t, mode);
      }
    } else {
      counts[(r - 7) * 256 + threadIdx.x] = 0;   // zero histogram
    }
  }
}

// ---------------------------------------------------------------------------
// knn flush (proven exact merge). u64 keys = exact lax.top_k order.
// ---------------------------------------------------------------------------
template<int CAP>
__device__ __forceinline__ void knn_flush(u64* __restrict__ wbuf, int& cnt,
                                          u64& val, u64& t15, float& th,
                                          int lane) {
  u64 cand = (lane < cnt) ? wbuf[lane] : ~0ull;
#pragma unroll
  for (int k = 2; k <= CAP; k <<= 1) {
#pragma unroll
    for (int j = k >> 1; j > 0; j >>= 1) {
      u64 other = shflxor64(cand, j);
      bool up    = ((lane & k) == 0) || (k == CAP);
      bool lower = ((lane & j) == 0);
      bool keepMin = (up == lower);
      u64 mn = cand < other ? cand : other;
      u64 mx = cand < other ? other : cand;
      cand = keepMin ? mn : mx;
    }
  }
  u64 rev = shfl64w16(cand, 15 - (lane & 15));
  u64 lo = val < rev ? val : rev;
#pragma unroll
  for (int j = 8; j > 0; j >>= 1) {
    u64 other = shflxor64(lo, j);
    bool lower = ((lane & j) == 0);
    u64 mn = lo < other ? lo : other;
    u64 mx = lo < other ? other : lo;
    lo = lower ? mn : mx;
  }
  val = (lane < 16) ? lo : ~0ull;
  t15 = shfl64(val, 15);
  u32 thb = (u32)(t15 >> 32);
  th = (thb == 0xffffffffu) ? 3.4e38f : __uint_as_float(thb);
  cnt = 0;
}

__global__ __launch_bounds__(256) void hist_kernel(
    const float4* __restrict__ pos4, const u32* __restrict__ bbx,
    int* __restrict__ counts, int* __restrict__ cid, int n) {
  const int i = blockIdx.x * 256 + threadIdx.x;
  if (i >= n) return;
  const float mnx = bdec(bbx[0]), mny = bdec(bbx[1]), mnz = bdec(bbx[2]);
  const float ihx = (float)GR / fmaxf(-bdec(bbx[3]) - mnx, 1e-20f);
  const float ihy = (float)GR / fmaxf(-bdec(bbx[4]) - mny, 1e-20f);
  const float ihz = (float)GR / fmaxf(-bdec(bbx[5]) - mnz, 1e-20f);
  float4 p = pos4[i];
  int cx = min(GR - 1, max(0, (int)((p.x - mnx) * ihx)));
  int cy = min(GR - 1, max(0, (int)((p.y - mny) * ihy)));
  int cz = min(GR - 1, max(0, (int)((p.z - mnz) * ihz)));
  int lin = (cz * GR + cy) * GR + cx;
  cid[i] = lin;
  atomicAdd(&counts[lin], 1);
}

// vectorized 1-block scan (int4 loads/stores).
__global__ __launch_bounds__(1024) void scan_kernel(
    const int* __restrict__ counts, int* __restrict__ cellstart,
    int* __restrict__ cursor) {
  __shared__ int part[1024];
  const int t = threadIdx.x;
  int4 v[8];
  int s = 0;
#pragma unroll
  for (int k = 0; k < 8; ++k) {
    v[k] = ((const int4*)counts)[t*8 + k];
    s += v[k].x + v[k].y + v[k].z + v[k].w;
  }
  part[t] = s;
  __syncthreads();
  for (int d = 1; d < 1024; d <<= 1) {
    int x = (t >= d) ? part[t - d] : 0;
    __syncthreads();
    part[t] += x;
    __syncthreads();
  }
  int o = part[t] - s;   // exclusive prefix of this 32-chunk
#pragma unroll
  for (int k = 0; k < 8; ++k) {
    int4 c;
    c.x = o; o += v[k].x;
    c.y = o; o += v[k].y;
    c.z = o; o += v[k].z;
    c.w = o; o += v[k].w;
    ((int4*)cellstart)[t*8 + k] = c;
    ((int4*)cursor)[t*8 + k] = c;
  }
  if (t == 1023) { cellstart[GR3] = o; cursor[GR3] = o; }
}

__global__ __launch_bounds__(256) void scatter_kernel(
    const float4* __restrict__ pos4, const int* __restrict__ cid,
    int* __restrict__ cursor, int* __restrict__ sidx,
    float4* __restrict__ spos4, int n) {
  const int i = blockIdx.x * 256 + threadIdx.x;
  if (i >= n) return;
  int dst = atomicAdd(&cursor[cid[i]], 1);
  spos4[dst] = pos4[i];
  sidx[dst]  = i;
}

// ---------------------------------------------------------------------------
// Grid KNN v7x2: ONE target per 128-thread block, TWO waves split the work.
// Post-mortems: inter-target rescheduling failed 3x (atomic steal 280us,
// strided-persistent 120us vs contiguous 105us) — the HW dispatcher's block
// backfill IS the load balancer; keep contiguous blocks. New lever: halve
// the per-target serial chain. Wave w handles alternate 64-blocks of each
// shell's segment space (and alternate 64-chunks of the seed cell); each
// wave keeps a private top-16 via the proven flush. Exactness: each half's
// 16th >= union's 16th, so th_block = min(thA,thB) >= true bound — filter
// and stop test stay conservative; true top-16 of the union is contained in
// (A's top16) u (B's top16), merged exactly by one knn_flush<32> over the
// 32 keys. Same u64 keys/sort -> bit-identical nbr. All barriers are
// block-uniform (break decisions from shared tot/mind2/th).
// ---------------------------------------------------------------------------
__global__ __launch_bounds__(128) void knn72_kernel(
    const float4* __restrict__ spos4,
    const int* __restrict__ sidx, const int* __restrict__ cellstart,
    const u32* __restrict__ bbx, int* __restrict__ nbr, int n) {
  __shared__ u64 buf[2][72];
  __shared__ u64 mrg[32];
  __shared__ float thsh[2];
  __shared__ int seensh[2];
  const int tid = threadIdx.x, lane = tid & 63, w = tid >> 6;   // w in {0,1}
  u64* wbuf = &buf[w][0];
  const int g = blockIdx.x;                 // contiguous: dispatcher balances
  const float4 pi = spos4[g];
  const int target = sidx[g];

  const float mnx = bdec(bbx[0]), mny = bdec(bbx[1]), mnz = bdec(bbx[2]);
  const float ex = fmaxf(-bdec(bbx[3]) - mnx, 1e-20f);
  const float ey = fmaxf(-bdec(bbx[4]) - mny, 1e-20f);
  const float ez = fmaxf(-bdec(bbx[5]) - mnz, 1e-20f);
  const float ihx = (float)GR / ex, ihy = (float)GR / ey, ihz = (float)GR / ez;
  const float hxf = ex * (1.0f / GR), hyf = ey * (1.0f / GR), hzf = ez * (1.0f / GR);
  const int cx = min(GR - 1, max(0, (int)((pi.x - mnx) * ihx)));
  const int cy = min(GR - 1, max(0, (int)((pi.y - mny) * ihy)));
  const int cz = min(GR - 1, max(0, (int)((pi.z - mnz) * ihz)));

  u64 val = ~0ull, t15 = ~0ull;
  float th = 3.4e38f;
  int cnt = 0;
  int myseen = 0;     // this wave's share; combined via LDS at shell ends

  auto doFlush = [&]() {
    if (cnt <= 32) knn_flush<32>(wbuf, cnt, val, t15, th, lane);
    else           knn_flush<64>(wbuf, cnt, val, t15, th, lane);
  };

  auto procSeg = [&](int p0, int p1) {
    for (int t0 = p0; t0 < p1; t0 += 64) {
      int gi = t0 + lane;
      bool in = gi < p1;
      float4 a = spos4[in ? gi : (p1 - 1)];
      float d2 = (pi.w + a.w) - 2.0f*(pi.x*a.x + pi.y*a.y + pi.z*a.z);  // frozen
      d2 = fmaxf(d2, 0.0f);
      bool pass = in && (d2 <= th);
      u64 bal = __ballot(pass);
      if (bal) {
        int pc = __popcll(bal);
        if (cnt + pc > 64) doFlush();
        u32 mb = __builtin_amdgcn_mbcnt_lo((u32)bal, 0u);
        mb = __builtin_amdgcn_mbcnt_hi((u32)(bal >> 32), mb);
        if (pass)
          wbuf[cnt + mb] = ((u64)__float_as_uint(d2) << 32) | (u32)sidx[gi];
        cnt += pc;
      }
    }
  };

  // seed: own cell; waves take alternate 64-chunks
  {
    const int oc = (cz * GR + cy) * GR + cx;
    const int oLo = cellstart[oc], oHi = cellstart[oc + 1];
    if (w == 0 && lane == 0) myseen += oHi - oLo;
    for (int t0 = oLo + w*64; t0 < oHi; t0 += 128) {
      int pe = min(t0 + 64, oHi);
      procSeg(t0, pe);
    }
    if (cnt > 0) doFlush();
    __syncthreads();
    thsh[w] = th;
    __syncthreads();
    th = fminf(thsh[0], thsh[1]);
  }

  for (int r = 1; r < GR; ++r) {
    const int x0 = max(cx - r, 0), x1 = min(cx + r, GR - 1);
    const int d1 = 2*r + 1, d2i = 2*r - 1;
    const int nA = 2 * d1;
    const int nB = 2 * d2i;
    const int nC = 2 * d2i * d2i;
    const int S = nA + nB + nC;
    const u32 magic = 0xFFFFFFFFu / (u32)d2i + 1u;

    // wave w decodes segment-index blocks [w*64, w*64+64), stride 128
    for (int b0 = w*64; b0 < S; b0 += 128) {
      const int s = b0 + lane;
      int zc = 0, yc = 0, xa = 0, xb = -1;
      bool live = s < S;
      if (live) {
        if (s < nA) {
          int za = s >= d1;
          int dy = s - (za ? d1 : 0) - r;
          zc = cz + (za ? r : -r); yc = cy + dy; xa = x0; xb = x1;
        } else if (s < nA + nB) {
          int t = s - nA;
          int side = t >= d2i;
          int dz = t - (side ? d2i : 0) - (r - 1);
          zc = cz + dz; yc = cy + (side ? r : -r); xa = x0; xb = x1;
        } else {
          int t = s - nA - nB;
          int side = t & 1; t >>= 1;
          int dzi = (int)__umulhi((u32)t, magic);
          int dyi = t - dzi * d2i;
          zc = cz - r + 1 + dzi; yc = cy - r + 1 + dyi;
          int xcell = side ? cx + r : cx - r;
          xa = xcell; xb = xcell;
          live = ((unsigned)xcell < GR);
        }
        live = live && ((unsigned)zc < GR) && ((unsigned)yc < GR);
      }
      int lo = 0, hi = 0;
      if (live) {
        int base = (zc * GR + yc) * GR;
        lo = cellstart[base + xa];
        hi = cellstart[base + xb + 1];
        myseen += hi - lo;
      }
      u64 bal = __ballot(live && (hi > lo));
      while (bal) {
        int l = __builtin_ctzll(bal); bal &= bal - 1;
        int p0 = __shfl(lo, l, 64), p1 = __shfl(hi, l, 64);
        procSeg(p0, p1);
      }
    }

    // exchange 1: seen totals + stale th (block-uniform decisions)
    int ms = myseen;
#pragma unroll
    for (int m = 32; m; m >>= 1) ms += __shfl_xor(ms, m, 64);
    __syncthreads();
    if (lane == 0) { seensh[w] = ms; thsh[w] = th; }
    __syncthreads();
    const int tot = seensh[0] + seensh[1];
    const float thStale = fminf(thsh[0], thsh[1]);
    if (tot >= n) break;                  // pending merged in final flush
    float mind = 3.4e38f;
    if (cx - r > 0)      mind = fminf(mind, pi.x - (mnx + (float)(cx - r) * hxf));
    if (cx + r < GR - 1) mind = fminf(mind, (mnx + (float)(cx + r + 1) * hxf) - pi.x);
    if (cy - r > 0)      mind = fminf(mind, pi.y - (mny + (float)(cy - r) * hyf));
    if (cy + r < GR - 1) mind = fminf(mind, (mny + (float)(cy + r + 1) * hyf) - pi.y);
    if (cz - r > 0)      mind = fminf(mind, pi.z - (mnz + (float)(cz - r) * hzf));
    if (cz + r < GR - 1) mind = fminf(mind, (mnz + (float)(cz + r + 1) * hzf) - pi.z);
    float mind2 = mind * mind * 0.9999f - 1e-6f;
    if (mind2 > thStale) break;           // stale screen (>= true bound)

    // exchange 2: flush, tighten to block-min th, retest
    if (cnt > 0) doFlush();
    __syncthreads();
    if (lane == 0) thsh[w] = th;
    __syncthreads();
    th = fminf(thsh[0], thsh[1]);
    if (mind2 > th) break;
  }
  if (cnt > 0) doFlush();

  // exact merge of the two waves' top-16s
  __syncthreads();
  if (lane < 16) mrg[w*16 + lane] = val;
  __syncthreads();
  if (w == 0) {
    u64 v2 = ~0ull, tt = ~0ull;
    float th2 = 3.4e38f;
    int c2 = 32;
    knn_flush<32>(mrg, c2, v2, tt, th2, lane);
    if (lane < 16) nbr[(size_t)target * 16 + lane] = (int)(v2 & 0xffffffffu);
  }
}

// ---------------------------------------------------------------------------
// MFMA conv v7 (proven best). GEMM1 weight prefetch; GEMM2 nt-outer, A in
// registers, fused epilogue. Numerics identical to round-5 version.
// ---------------------------------------------------------------------------
template<int CIN, int CMID, int KT1, int NT, int KT2>
__global__ __launch_bounds__(256, 4) void conv_mfma7_kernel(
    const float* __restrict__ xf,             // [N,6] fp32 (CIN==6)
    const unsigned short* __restrict__ xb,    // [N,64] bf16 (CIN==64)
    const float4* __restrict__ pos4,
    const int* __restrict__ nbr,
    const int* __restrict__ flag,
    const unsigned short* __restrict__ WaT,   // [CMID][K1PAD] bf16
    const unsigned short* __restrict__ WbT,   // [CMID][CMID]  bf16
    const float* __restrict__ baf,
    const float* __restrict__ gmf,
    const float* __restrict__ btf,
    const float* __restrict__ bbf,
    unsigned short* __restrict__ xoutb,       // [N,CMID] bf16 ws (may be null)
    void* __restrict__ bout, size_t out_off)
{
  constexpr int K1PAD = KT1 * 32;
  constexpr int SB = CMID + 8;

  __shared__ unsigned short msgB[128 * SB];

  const int tid  = threadIdx.x;
  const int lane = tid & 63;
  const int w    = tid >> 6;
  const int quad = lane >> 4;
  const int cl   = lane & 15;
  const int node0 = blockIdx.x * 8;
  const int mode = flag[0];

  bf16x8 afr[2][KT1];
#pragma unroll
  for (int mt = 0; mt < 2; ++mt) {
    const int node = node0 + w*2 + mt;
    const int j = nbr[(size_t)node*16 + cl];
    const float4 pin = pos4[node];
    const float4 pj = pos4[j];
    const float rx = pj.x - pin.x, ry = pj.y - pin.y, rz = pj.z - pin.z;
    if constexpr (CIN == 64) {
#pragma unroll
      for (int kt = 0; kt < 2; ++kt)
        afr[mt][kt] = *(const bf16x8*)&xb[(size_t)j*64 + kt*32 + quad*8];
      unsigned short o[8] = {0,0,0,0,0,0,0,0};
      if (quad == 0) { o[0] = f2bfb(rx); o[1] = f2bfb(ry); o[2] = f2bfb(rz); }
      afr[mt][KT1-1] = *(bf16x8*)o;
    } else {  // CIN == 6
      unsigned short o[8] = {0,0,0,0,0,0,0,0};
      if (quad == 0) {
        const float* p = &xf[(size_t)j*6];
        o[0] = f2bfb(p[0]); o[1] = f2bfb(p[1]); o[2] = f2bfb(p[2]);
        o[3] = f2bfb(p[3]); o[4] = f2bfb(p[4]); o[5] = f2bfb(p[5]);
        o[6] = f2bfb(rx);   o[7] = f2bfb(ry);
      } else if (quad == 1) {
        o[0] = f2bfb(rz);
      }
      afr[mt][0] = *(bf16x8*)o;
    }
  }

  // ---- GEMM1 + bias + GN, one N-tile at a time; weights prefetched ----
  const int grow = lane >> 1, ggl = lane & 1;    // GN thread mapping
  bf16x8 w1c[KT1], w1n[KT1];
#pragma unroll
  for (int kt = 0; kt < KT1; ++kt)
    w1c[kt] = *(const bf16x8*)&WaT[(size_t)cl * K1PAD + kt*32 + quad*8];
#pragma unroll
  for (int nt = 0; nt < NT; ++nt) {
    if (nt + 1 < NT) {
#pragma unroll
      for (int kt = 0; kt < KT1; ++kt)
        w1n[kt] = *(const bf16x8*)&WaT[(size_t)((nt+1)*16 + cl) * K1PAD + kt*32 + quad*8];
    }
    f32x4 a1[2];
    a1[0] = (f32x4){0.f, 0.f, 0.f, 0.f};
    a1[1] = (f32x4){0.f, 0.f, 0.f, 0.f};
#pragma unroll
    for (int kt = 0; kt < KT1; ++kt) {
      a1[0] = __builtin_amdgcn_mfma_f32_16x16x32_bf16(afr[0][kt], w1c[kt], a1[0], 0, 0, 0);
      a1[1] = __builtin_amdgcn_mfma_f32_16x16x32_bf16(afr[1][kt], w1c[kt], a1[1], 0, 0, 0);
    }
    float bac = baf[nt*16 + cl];
#pragma unroll
    for (int mt = 0; mt < 2; ++mt)
#pragma unroll
      for (int reg = 0; reg < 4; ++reg)
        msgB[(w*32 + mt*16 + quad*4 + reg) * SB + nt*16 + cl] =
            f2bfb(a1[mt][reg] + bac);
    asm volatile("" ::: "memory");   // same-wave DS FIFO: write < read
    {
      const int cb = nt*16 + ggl*8;
      unsigned short* p = &msgB[(w*32 + grow) * SB + cb];
      u16x8 hv = *(const u16x8*)p;
      float vv[8];
#pragma unroll
      for (int e = 0; e < 8; ++e) vv[e] = bfb2f(hv[e]);
      float s = 0.f, q = 0.f;
#pragma unroll
      for (int e = 0; e < 8; ++e) { s += vv[e]; q += vv[e]*vv[e]; }
      float mu = s * 0.125f;
      float var = q * 0.125f - mu * mu;
      float inv = rsqrtf(fmaxf(var, 0.0f) + 1e-5f);
      unsigned short o[8];
#pragma unroll
      for (int e = 0; e < 8; ++e) {
        float t = (vv[e] - mu) * inv * gmf[cb+e] + btf[cb+e];
        o[e] = f2bfb(fmaxf(t, 0.0f));
      }
      *(bf16x8*)p = *(bf16x8*)o;
    }
    asm volatile("" ::: "memory");
#pragma unroll
    for (int kt = 0; kt < KT1; ++kt) w1c[kt] = w1n[kt];
  }

  // ---- GEMM2: A-fragments to registers once; nt-outer with fused epilogue
  bf16x8 af0[KT2], af1[KT2];
#pragma unroll
  for (int kt = 0; kt < KT2; ++kt) {
    af0[kt] = *(const bf16x8*)&msgB[(w*32 + cl)      * SB + kt*32 + quad*8];
    af1[kt] = *(const bf16x8*)&msgB[(w*32 + 16 + cl) * SB + kt*32 + quad*8];
  }
  bf16x8 w2c[KT2], w2n[KT2];
#pragma unroll
  for (int kt = 0; kt < KT2; ++kt)
    w2c[kt] = *(const bf16x8*)&WbT[(size_t)cl * CMID + kt*32 + quad*8];
#pragma unroll
  for (int nt = 0; nt < NT; ++nt) {
    if (nt + 1 < NT) {
#pragma unroll
      for (int kt = 0; kt < KT2; ++kt)
        w2n[kt] = *(const bf16x8*)&WbT[(size_t)((nt+1)*16 + cl) * CMID + kt*32 + quad*8];
    }
    f32x4 a2[2];
    a2[0] = (f32x4){0.f, 0.f, 0.f, 0.f};
    a2[1] = (f32x4){0.f, 0.f, 0.f, 0.f};
#pragma unroll
    for (int kt = 0; kt < KT2; ++kt) {
      a2[0] = __builtin_amdgcn_mfma_f32_16x16x32_bf16(af0[kt], w2c[kt], a2[0], 0, 0, 0);
      a2[1] = __builtin_amdgcn_mfma_f32_16x16x32_bf16(af1[kt], w2c[kt], a2[1], 0, 0, 0);
    }
#pragma unroll
    for (int mt = 0; mt < 2; ++mt) {
      int node = node0 + w*2 + mt;
      float m = fmaxf(fmaxf(a2[mt][0], a2[mt][1]),
                      fmaxf(a2[mt][2], a2[mt][3]));
      m = fmaxf(m, __shfl_xor(m, 16, 64));
      m = fmaxf(m, __shfl_xor(m, 32, 64));
      float v = fmaxf(m + bbf[nt*16 + cl], 0.0f);
      if (quad == 0) {
        size_t oi = (size_t)node * CMID + nt*16 + cl;
        if (xoutb) xoutb[oi] = f2bfb(v);
        stv(bout, out_off + oi, mode, v);
      }
    }
#pragma unroll
    for (int kt = 0; kt < KT2; ++kt) w2c[kt] = w2n[kt];
  }
}

// ---------------------------------------------------------------------------
extern "C" void kernel_launch(void* const* d_in, const int* in_sizes, int n_in,
                              void* d_out, int out_size, void* d_ws, size_t ws_size,
                              hipStream_t stream) {
  (void)n_in; (void)ws_size; (void)in_sizes;
  int n = out_size / 256;
  if (n <= 0 || (n & 255)) n = 16384;

  float* ws = (float*)d_ws;
  int*    flag    = (int*)ws;                                       // 16 ints (0=mode, 4..9=bbox atomics)
  float4* pos4    = (float4*)(ws + 16);                             // 4n
  float*  h0      = ws + 16 + (size_t)4*n;                          // 6n
  int*    nbr     = (int*)(ws + 16 + (size_t)10*n);                 // 16n
  unsigned short* h1b = (unsigned short*)(ws + 16 + (size_t)26*n);  // 32n
  unsigned short* h2b = (unsigned short*)(ws + 16 + (size_t)58*n);  // 32n
  float*  vbuf    = ws + 16 + (size_t)90*n;                         // 1024
  unsigned short* wtbuf = (unsigned short*)(vbuf + 1024);           // 45056 shorts

  // grid-knn buffers (after wtbuf = 22528 floats)
  float* gbase = vbuf + 1024 + 22528;
  int*    cid       = (int*)gbase;            // n
  int*    counts    = cid + n;                // 32768
  int*    cellstart = counts + GR3;           // 32769 (padded to 32772)
  int*    cursor    = cellstart + 32772;      // 32769 (padded to 32772)
  int*    sidx      = cursor + 32772;         // n
  float4* spos4     = (float4*)(sidx + n);    // 4n floats (16B aligned)

  const int vsz[12] = {64,64,64,64, 64,64,64,64, 128,128,128,128};
  const int vsrc[12] = {3,4,5,7, 9,10,11,13, 15,16,17,19};
  CvtArgs ca;
  float* vptr[12];
  {
    int off = 0;
    for (int t = 0; t < 12; ++t) {
      ca.e[t].src = d_in[vsrc[t]];
      ca.e[t].dst = vbuf + off;
      ca.e[t].n   = vsz[t];
      vptr[t] = vbuf + off;
      off += vsz[t];
    }
  }
  const int wK[6]    = {9, 64, 67, 64, 67, 128};
  const int wN[6]    = {64, 64, 64, 64, 128, 128};
  const int wKp[6]   = {32, 64, 96, 64, 96, 128};
  const int wsrc[6]  = {2, 6, 8, 12, 14, 18};
  WArgs wa;
  unsigned short* wptr[6];
  {
    int off = 0;
    for (int t = 0; t < 6; ++t) {
      wa.e[t].src  = d_in[wsrc[t]];
      wa.e[t].dst  = wtbuf + off;
      wa.e[t].K    = wK[t];
      wa.e[t].N    = wN[t];
      wa.e[t].Kpad = wKp[t];
      wptr[t] = wtbuf + off;
      off += wN[t] * wKp[t];
    }
  }

  // ONE memset: all six bbox slots init to 0xFF (max stored as benc(-x))
  u32* bbx = (u32*)ws + 4;
  hipMemsetAsync(bbx, 0xFF, 24, stream);

  setup_kernel<<<n/256 + 7 + GR3/256, 256, 0, stream>>>(
      d_in[0], d_in[1], wa, ca, flag, pos4, h0, counts, n);

  hist_kernel<<<n/256, 256, 0, stream>>>(pos4, bbx, counts, cid, n);
  scan_kernel<<<1, 1024, 0, stream>>>(counts, cellstart, cursor);
  scatter_kernel<<<n/256, 256, 0, stream>>>(pos4, cid, cursor, sidx, spos4, n);
  knn72_kernel<<<n, 128, 0, stream>>>(spos4, sidx, cellstart, bbx, nbr, n);

  // <CIN, CMID, KT1, NT, KT2>
  conv_mfma7_kernel<6, 64, 1, 4, 2><<<n/8, 256, 0, stream>>>(
      h0, (const unsigned short*)nullptr, pos4, nbr, flag, wptr[0], wptr[1],
      vptr[0], vptr[1], vptr[2], vptr[3], h1b, d_out, (size_t)0);
  conv_mfma7_kernel<64, 64, 3, 4, 2><<<n/8, 256, 0, stream>>>(
      (const float*)nullptr, h1b, pos4, nbr, flag, wptr[2], wptr[3],
      vptr[4], vptr[5], vptr[6], vptr[7], h2b, d_out, (size_t)n*64);
  conv_mfma7_kernel<64, 128, 3, 8, 4><<<n/8, 256, 0, stream>>>(
      (const float*)nullptr, h2b, pos4, nbr, flag, wptr[4], wptr[5],
      vptr[8], vptr[9], vptr[10], vptr[11],
      (unsigned short*)nullptr, d_out, (size_t)n*128);
}

// Round 11
// 349.983 us; speedup vs baseline: 1.0990x; 1.0990x over previous
//
#include <hip/hip_runtime.h>
#include <hip/hip_bf16.h>
#include <stdint.h>

typedef unsigned long long u64;
typedef unsigned int u32;
typedef __attribute__((ext_vector_type(8))) short bf16x8;
typedef __attribute__((ext_vector_type(8))) unsigned short u16x8;
typedef __attribute__((ext_vector_type(4))) float f32x4;

__device__ __forceinline__ float ldv(const void* p, size_t idx, int mode) {
  return mode ? __bfloat162float(((const __hip_bfloat16*)p)[idx])
              : ((const float*)p)[idx];
}
__device__ __forceinline__ void stv(void* p, size_t idx, int mode, float v) {
  if (mode) ((__hip_bfloat16*)p)[idx] = __float2bfloat16(v);
  else      ((float*)p)[idx] = v;
}
__device__ __forceinline__ unsigned short f2bfb(float f) {  // RNE f32->bf16 bits
  u32 u = __float_as_uint(f);
  u32 r = u + 0x7fffu + ((u >> 16) & 1u);
  return (unsigned short)(r >> 16);
}
__device__ __forceinline__ float bfb2f(unsigned short b) {
  return __uint_as_float((u32)b << 16);
}
__device__ __forceinline__ u64 shfl64(u64 v, int src) {
  int lo = __shfl((int)(u32)(v & 0xffffffffu), src, 64);
  int hi = __shfl((int)(u32)(v >> 32), src, 64);
  return ((u64)(u32)hi << 32) | (u32)lo;
}
__device__ __forceinline__ u64 shflxor64(u64 v, int m) {
  int lo = __shfl_xor((int)(u32)(v & 0xffffffffu), m, 64);
  int hi = __shfl_xor((int)(u32)(v >> 32), m, 64);
  return ((u64)(u32)hi << 32) | (u32)lo;
}
__device__ __forceinline__ u64 shfl64w16(u64 v, int src) {  // width-16 shfl
  int lo = __shfl((int)(u32)(v & 0xffffffffu), src, 16);
  int hi = __shfl((int)(u32)(v >> 32), src, 16);
  return ((u64)(u32)hi << 32) | (u32)lo;
}

// monotonic float<->uint encoding for atomicMin-based bbox.
// Max is stored as benc(-x) so BOTH min and max slots init to 0xFF and use
// atomicMin; decode max = -bdec(slot). Negation is exact -> identical grid.
__device__ __forceinline__ u32 benc(float f) {
  u32 u = __float_as_uint(f);
  return (u & 0x80000000u) ? ~u : (u | 0x80000000u);
}
__device__ __forceinline__ float bdec(u32 k) {
  return (k & 0x80000000u) ? __uint_as_float(k ^ 0x80000000u)
                           : __uint_as_float(~k);
}

__global__ void PointNetSimple_61409442398998_kernel() {}

// ---------------------------------------------------------------------------
// setup: dtype-detect + weight transpose/convert + vector cvt + prep +
// bbox atomics + counts zeroing (fused).
// ---------------------------------------------------------------------------
struct CvtEnt { const void* src; float* dst; int n; };
struct CvtArgs { CvtEnt e[12]; };
struct WEnt { const void* src; unsigned short* dst; int K, N, Kpad; };
struct WArgs { WEnt e[6]; };

#define GR 32
#define GR3 (GR*GR*GR)

__global__ void setup_kernel(const void* __restrict__ pos,
                             const void* __restrict__ nrm,
                             WArgs wa, CvtArgs ca,
                             int* __restrict__ flag,
                             float4* __restrict__ pos4,
                             float* __restrict__ h0,
                             int* __restrict__ counts, int n) {
  const unsigned short* u16p = (const unsigned short*)pos;
  int cnt = 0;
  for (int k = 0; k < 32; ++k) {
    int e = (u16p[k] >> 7) & 0xff;
    if (e >= 110 && e <= 140) cnt++;
  }
  const int mode = (cnt >= 26) ? 1 : 0;

  const int nprep = n >> 8;
  const int b = blockIdx.x;
  if (b < nprep) {
    int i = b * 256 + threadIdx.x;
    float x = ldv(pos, 3*(size_t)i+0, mode);
    float y = ldv(pos, 3*(size_t)i+1, mode);
    float z = ldv(pos, 3*(size_t)i+2, mode);
    pos4[i] = make_float4(x, y, z, x*x + y*y + z*z);
    h0[6*(size_t)i+0] = x; h0[6*(size_t)i+1] = y; h0[6*(size_t)i+2] = z;
    h0[6*(size_t)i+3] = ldv(nrm, 3*(size_t)i+0, mode);
    h0[6*(size_t)i+4] = ldv(nrm, 3*(size_t)i+1, mode);
    h0[6*(size_t)i+5] = ldv(nrm, 3*(size_t)i+2, mode);
    // bbox contribution (bbx = ((u32*)flag)+4..9, all init'd to 0xFF)
    float bmn[3] = {x, y, z}, bmx[3] = {x, y, z};
#pragma unroll
    for (int m = 32; m; m >>= 1) {
#pragma unroll
      for (int k = 0; k < 3; ++k) {
        bmn[k] = fminf(bmn[k], __shfl_xor(bmn[k], m, 64));
        bmx[k] = fmaxf(bmx[k], __shfl_xor(bmx[k], m, 64));
      }
    }
    if ((threadIdx.x & 63) == 0) {
      u32* bb = (u32*)flag;
#pragma unroll
      for (int k = 0; k < 3; ++k) {
        atomicMin(&bb[4 + k], benc(bmn[k]));
        atomicMin(&bb[7 + k], benc(-bmx[k]));   // max via negated-min
      }
    }
  } else {
    int r = b - nprep;
    if (r < 6) {
      WEnt ent = wa.e[r];
      for (int t = threadIdx.x; t < ent.N * ent.Kpad; t += blockDim.x) {
        int nn = t / ent.Kpad;
        int k  = t - nn * ent.Kpad;
        float v = (k < ent.K) ? ldv(ent.src, (size_t)k * ent.N + nn, mode) : 0.0f;
        ent.dst[t] = f2bfb(v);
      }
      if (r == 0 && threadIdx.x == 0) flag[0] = mode;
    } else if (r == 6) {
      for (int t2 = 0; t2 < 12; ++t2) {
        CvtEnt ent = ca.e[t2];
        for (int t = threadIdx.x; t < ent.n; t += blockDim.x)
          ent.dst[t] = ldv(ent.src, t, mode);
      }
    } else {
      counts[(r - 7) * 256 + threadIdx.x] = 0;   // zero histogram
    }
  }
}

// ---------------------------------------------------------------------------
// knn flush (proven exact merge). u64 keys = exact lax.top_k order.
// NaN-guard: sentinel -> +inf threshold.
// ---------------------------------------------------------------------------
template<int CAP>
__device__ __forceinline__ void knn_flush(u64* __restrict__ wbuf, int& cnt,
                                          u64& val, u64& t15, float& th,
                                          int lane) {
  u64 cand = (lane < cnt) ? wbuf[lane] : ~0ull;
#pragma unroll
  for (int k = 2; k <= CAP; k <<= 1) {
#pragma unroll
    for (int j = k >> 1; j > 0; j >>= 1) {
      u64 other = shflxor64(cand, j);
      bool up    = ((lane & k) == 0) || (k == CAP);
      bool lower = ((lane & j) == 0);
      bool keepMin = (up == lower);
      u64 mn = cand < other ? cand : other;
      u64 mx = cand < other ? other : cand;
      cand = keepMin ? mn : mx;
    }
  }
  u64 rev = shfl64w16(cand, 15 - (lane & 15));
  u64 lo = val < rev ? val : rev;
#pragma unroll
  for (int j = 8; j > 0; j >>= 1) {
    u64 other = shflxor64(lo, j);
    bool lower = ((lane & j) == 0);
    u64 mn = lo < other ? lo : other;
    u64 mx = lo < other ? other : lo;
    lo = lower ? mn : mx;
  }
  val = (lane < 16) ? lo : ~0ull;
  t15 = shfl64(val, 15);
  u32 thb = (u32)(t15 >> 32);
  th = (thb == 0xffffffffu) ? 3.4e38f : __uint_as_float(thb);
  cnt = 0;
}

__global__ __launch_bounds__(256) void hist_kernel(
    const float4* __restrict__ pos4, const u32* __restrict__ bbx,
    int* __restrict__ counts, int* __restrict__ cid, int n) {
  const int i = blockIdx.x * 256 + threadIdx.x;
  if (i >= n) return;
  const float mnx = bdec(bbx[0]), mny = bdec(bbx[1]), mnz = bdec(bbx[2]);
  const float ihx = (float)GR / fmaxf(-bdec(bbx[3]) - mnx, 1e-20f);
  const float ihy = (float)GR / fmaxf(-bdec(bbx[4]) - mny, 1e-20f);
  const float ihz = (float)GR / fmaxf(-bdec(bbx[5]) - mnz, 1e-20f);
  float4 p = pos4[i];
  int cx = min(GR - 1, max(0, (int)((p.x - mnx) * ihx)));
  int cy = min(GR - 1, max(0, (int)((p.y - mny) * ihy)));
  int cz = min(GR - 1, max(0, (int)((p.z - mnz) * ihz)));
  int lin = (cz * GR + cy) * GR + cx;
  cid[i] = lin;
  atomicAdd(&counts[lin], 1);
}

// vectorized 1-block scan (int4 loads/stores).
__global__ __launch_bounds__(1024) void scan_kernel(
    const int* __restrict__ counts, int* __restrict__ cellstart,
    int* __restrict__ cursor) {
  __shared__ int part[1024];
  const int t = threadIdx.x;
  int4 v[8];
  int s = 0;
#pragma unroll
  for (int k = 0; k < 8; ++k) {
    v[k] = ((const int4*)counts)[t*8 + k];
    s += v[k].x + v[k].y + v[k].z + v[k].w;
  }
  part[t] = s;
  __syncthreads();
  for (int d = 1; d < 1024; d <<= 1) {
    int x = (t >= d) ? part[t - d] : 0;
    __syncthreads();
    part[t] += x;
    __syncthreads();
  }
  int o = part[t] - s;   // exclusive prefix of this 32-chunk
#pragma unroll
  for (int k = 0; k < 8; ++k) {
    int4 c;
    c.x = o; o += v[k].x;
    c.y = o; o += v[k].y;
    c.z = o; o += v[k].z;
    c.w = o; o += v[k].w;
    ((int4*)cellstart)[t*8 + k] = c;
    ((int4*)cursor)[t*8 + k] = c;
  }
  if (t == 1023) { cellstart[GR3] = o; cursor[GR3] = o; }
}

__global__ __launch_bounds__(256) void scatter_kernel(
    const float4* __restrict__ pos4, const int* __restrict__ cid,
    int* __restrict__ cursor, int* __restrict__ sidx,
    float4* __restrict__ spos4, int n) {
  const int i = blockIdx.x * 256 + threadIdx.x;
  if (i >= n) return;
  int dst = atomicAdd(&cursor[cid[i]], 1);
  spos4[dst] = pos4[i];
  sidx[dst]  = i;
}

// ---------------------------------------------------------------------------
// Grid KNN v7 (proven 105us — RESTORED). Contiguous static blocks (the HW
// dispatcher's block backfill is the load balancer; all rescheduling
// attempts regressed: atomic-steal 280us, strided-persistent 120us, 2-wave
// split 140us). Exact-shell enumeration, lane-parallel cellstart loads,
// stale-th stop screen. nbr bit-identical to lax.top_k.
// ---------------------------------------------------------------------------
#define KNN7_WPB 4
__global__ __launch_bounds__(256) void knn7_kernel(
    const float4* __restrict__ spos4,
    const int* __restrict__ sidx, const int* __restrict__ cellstart,
    const u32* __restrict__ bbx, int* __restrict__ nbr, int n) {
  __shared__ u64 buf[KNN7_WPB][72];
  const int tid = threadIdx.x, lane = tid & 63, w = tid >> 6;
  const int g = blockIdx.x * KNN7_WPB + w;
  u64* wbuf = &buf[w][0];
  const float4 pi = spos4[g];       // targets in cell-sorted order
  const int target = sidx[g];

  const float mnx = bdec(bbx[0]), mny = bdec(bbx[1]), mnz = bdec(bbx[2]);
  const float ex = fmaxf(-bdec(bbx[3]) - mnx, 1e-20f);
  const float ey = fmaxf(-bdec(bbx[4]) - mny, 1e-20f);
  const float ez = fmaxf(-bdec(bbx[5]) - mnz, 1e-20f);
  const float ihx = (float)GR / ex, ihy = (float)GR / ey, ihz = (float)GR / ez;
  const float hxf = ex * (1.0f / GR), hyf = ey * (1.0f / GR), hzf = ez * (1.0f / GR);
  const int cx = min(GR - 1, max(0, (int)((pi.x - mnx) * ihx)));
  const int cy = min(GR - 1, max(0, (int)((pi.y - mny) * ihy)));
  const int cz = min(GR - 1, max(0, (int)((pi.z - mnz) * ihz)));

  u64 val = ~0ull, t15 = ~0ull;
  float th = 3.4e38f;
  int cnt = 0;
  int myseen = 0;   // per-lane partial; reduced at break checks

  auto doFlush = [&]() {
    if (cnt <= 32) knn_flush<32>(wbuf, cnt, val, t15, th, lane);
    else           knn_flush<64>(wbuf, cnt, val, t15, th, lane);
  };

  auto procSeg = [&](int p0, int p1) {
#pragma unroll 2
    for (int t0 = p0; t0 < p1; t0 += 64) {
      int gi = t0 + lane;
      bool in = gi < p1;
      float4 a = spos4[in ? gi : (p1 - 1)];
      float d2 = (pi.w + a.w) - 2.0f*(pi.x*a.x + pi.y*a.y + pi.z*a.z);  // frozen
      d2 = fmaxf(d2, 0.0f);
      bool pass = in && (d2 <= th);
      u64 bal = __ballot(pass);
      if (bal) {
        int pc = __popcll(bal);
        if (cnt + pc > 64) doFlush();
        u32 mb = __builtin_amdgcn_mbcnt_lo((u32)bal, 0u);
        mb = __builtin_amdgcn_mbcnt_hi((u32)(bal >> 32), mb);
        if (pass)
          wbuf[cnt + mb] = ((u64)__float_as_uint(d2) << 32) | (u32)sidx[gi];
        cnt += pc;
      }
    }
  };

  // shell r=0: own cell (seeds th before shell-1)
  {
    const int oc = (cz * GR + cy) * GR + cx;
    const int oLo = cellstart[oc], oHi = cellstart[oc + 1];
    if (lane == 0) myseen += oHi - oLo;
    procSeg(oLo, oHi);
    if (cnt > 0) doFlush();
  }

  for (int r = 1; r < GR; ++r) {
    const int x0 = max(cx - r, 0), x1 = min(cx + r, GR - 1);
    const int d1 = 2*r + 1, d2i = 2*r - 1;
    const int nA = 2 * d1;            // top/bottom slabs: 2 x (2r+1) rows
    const int nB = 2 * d2i;           // interior slabs, side rows
    const int nC = 2 * d2i * d2i;     // interior z,y: x-face cells
    const int S = nA + nB + nC;
    const u32 magic = 0xFFFFFFFFu / (u32)d2i + 1u;  // exact for our t range

    for (int b0 = 0; b0 < S; b0 += 64) {
      const int s = b0 + lane;
      int zc = 0, yc = 0, xa = 0, xb = -1;
      bool live = s < S;
      if (live) {
        if (s < nA) {
          int za = s >= d1;
          int dy = s - (za ? d1 : 0) - r;
          zc = cz + (za ? r : -r); yc = cy + dy; xa = x0; xb = x1;
        } else if (s < nA + nB) {
          int t = s - nA;
          int side = t >= d2i;
          int dz = t - (side ? d2i : 0) - (r - 1);
          zc = cz + dz; yc = cy + (side ? r : -r); xa = x0; xb = x1;
        } else {
          int t = s - nA - nB;
          int side = t & 1; t >>= 1;
          int dzi = (int)__umulhi((u32)t, magic);
          int dyi = t - dzi * d2i;
          zc = cz - r + 1 + dzi; yc = cy - r + 1 + dyi;
          int xcell = side ? cx + r : cx - r;
          xa = xcell; xb = xcell;
          live = ((unsigned)xcell < GR);
        }
        live = live && ((unsigned)zc < GR) && ((unsigned)yc < GR);
      }
      int lo = 0, hi = 0;
      if (live) {
        int base = (zc * GR + yc) * GR;
        lo = cellstart[base + xa];
        hi = cellstart[base + xb + 1];
        myseen += hi - lo;
      }
      u64 bal = __ballot(live && (hi > lo));
      while (bal) {
        int l = __builtin_ctzll(bal); bal &= bal - 1;
        int p0 = __shfl(lo, l, 64), p1 = __shfl(hi, l, 64);
        procSeg(p0, p1);
      }
    }

    // total seen (wave-uniform)
    int tot = myseen;
#pragma unroll
    for (int m = 32; m; m >>= 1) tot += __shfl_xor(tot, m, 64);
    if (tot >= n) break;        // everything examined (pending merged below)
    // unseen points lie outside box r; min distance to its interior faces
    float mind = 3.4e38f;
    if (cx - r > 0)      mind = fminf(mind, pi.x - (mnx + (float)(cx - r) * hxf));
    if (cx + r < GR - 1) mind = fminf(mind, (mnx + (float)(cx + r + 1) * hxf) - pi.x);
    if (cy - r > 0)      mind = fminf(mind, pi.y - (mny + (float)(cy - r) * hyf));
    if (cy + r < GR - 1) mind = fminf(mind, (mny + (float)(cy + r + 1) * hyf) - pi.y);
    if (cz - r > 0)      mind = fminf(mind, pi.z - (mnz + (float)(cz - r) * hzf));
    if (cz + r < GR - 1) mind = fminf(mind, (mnz + (float)(cz + r + 1) * hzf) - pi.z);
    float mind2 = mind * mind * 0.9999f - 1e-6f;   // margin >> fp rounding
    if (mind2 > th) break;      // stale-th screen (th >= true 16th: valid)
    if (cnt > 0) {
      doFlush();                // tighten th, then retest
      if (mind2 > th) break;
    }
  }
  if (cnt > 0) doFlush();
  if (lane < 16) nbr[(size_t)target * 16 + lane] = (int)(val & 0xffffffffu);
}

// ---------------------------------------------------------------------------
// MFMA conv v7 (proven best). GEMM1 weight prefetch; GEMM2 nt-outer, A in
// registers, fused epilogue. Numerics identical to round-5 version.
// ---------------------------------------------------------------------------
template<int CIN, int CMID, int KT1, int NT, int KT2>
__global__ __launch_bounds__(256, 4) void conv_mfma7_kernel(
    const float* __restrict__ xf,             // [N,6] fp32 (CIN==6)
    const unsigned short* __restrict__ xb,    // [N,64] bf16 (CIN==64)
    const float4* __restrict__ pos4,
    const int* __restrict__ nbr,
    const int* __restrict__ flag,
    const unsigned short* __restrict__ WaT,   // [CMID][K1PAD] bf16
    const unsigned short* __restrict__ WbT,   // [CMID][CMID]  bf16
    const float* __restrict__ baf,
    const float* __restrict__ gmf,
    const float* __restrict__ btf,
    const float* __restrict__ bbf,
    unsigned short* __restrict__ xoutb,       // [N,CMID] bf16 ws (may be null)
    void* __restrict__ bout, size_t out_off)
{
  constexpr int K1PAD = KT1 * 32;
  constexpr int SB = CMID + 8;

  __shared__ unsigned short msgB[128 * SB];

  const int tid  = threadIdx.x;
  const int lane = tid & 63;
  const int w    = tid >> 6;
  const int quad = lane >> 4;
  const int cl   = lane & 15;
  const int node0 = blockIdx.x * 8;
  const int mode = flag[0];

  bf16x8 afr[2][KT1];
#pragma unroll
  for (int mt = 0; mt < 2; ++mt) {
    const int node = node0 + w*2 + mt;
    const int j = nbr[(size_t)node*16 + cl];
    const float4 pin = pos4[node];
    const float4 pj = pos4[j];
    const float rx = pj.x - pin.x, ry = pj.y - pin.y, rz = pj.z - pin.z;
    if constexpr (CIN == 64) {
#pragma unroll
      for (int kt = 0; kt < 2; ++kt)
        afr[mt][kt] = *(const bf16x8*)&xb[(size_t)j*64 + kt*32 + quad*8];
      unsigned short o[8] = {0,0,0,0,0,0,0,0};
      if (quad == 0) { o[0] = f2bfb(rx); o[1] = f2bfb(ry); o[2] = f2bfb(rz); }
      afr[mt][KT1-1] = *(bf16x8*)o;
    } else {  // CIN == 6
      unsigned short o[8] = {0,0,0,0,0,0,0,0};
      if (quad == 0) {
        const float* p = &xf[(size_t)j*6];
        o[0] = f2bfb(p[0]); o[1] = f2bfb(p[1]); o[2] = f2bfb(p[2]);
        o[3] = f2bfb(p[3]); o[4] = f2bfb(p[4]); o[5] = f2bfb(p[5]);
        o[6] = f2bfb(rx);   o[7] = f2bfb(ry);
      } else if (quad == 1) {
        o[0] = f2bfb(rz);
      }
      afr[mt][0] = *(bf16x8*)o;
    }
  }

  // ---- GEMM1 + bias + GN, one N-tile at a time; weights prefetched ----
  const int grow = lane >> 1, ggl = lane & 1;    // GN thread mapping
  bf16x8 w1c[KT1], w1n[KT1];
#pragma unroll
  for (int kt = 0; kt < KT1; ++kt)
    w1c[kt] = *(const bf16x8*)&WaT[(size_t)cl * K1PAD + kt*32 + quad*8];
#pragma unroll
  for (int nt = 0; nt < NT; ++nt) {
    if (nt + 1 < NT) {
#pragma unroll
      for (int kt = 0; kt < KT1; ++kt)
        w1n[kt] = *(const bf16x8*)&WaT[(size_t)((nt+1)*16 + cl) * K1PAD + kt*32 + quad*8];
    }
    f32x4 a1[2];
    a1[0] = (f32x4){0.f, 0.f, 0.f, 0.f};
    a1[1] = (f32x4){0.f, 0.f, 0.f, 0.f};
#pragma unroll
    for (int kt = 0; kt < KT1; ++kt) {
      a1[0] = __builtin_amdgcn_mfma_f32_16x16x32_bf16(afr[0][kt], w1c[kt], a1[0], 0, 0, 0);
      a1[1] = __builtin_amdgcn_mfma_f32_16x16x32_bf16(afr[1][kt], w1c[kt], a1[1], 0, 0, 0);
    }
    float bac = baf[nt*16 + cl];
#pragma unroll
    for (int mt = 0; mt < 2; ++mt)
#pragma unroll
      for (int reg = 0; reg < 4; ++reg)
        msgB[(w*32 + mt*16 + quad*4 + reg) * SB + nt*16 + cl] =
            f2bfb(a1[mt][reg] + bac);
    asm volatile("" ::: "memory");   // same-wave DS FIFO: write < read
    {
      const int cb = nt*16 + ggl*8;
      unsigned short* p = &msgB[(w*32 + grow) * SB + cb];
      u16x8 hv = *(const u16x8*)p;
      float vv[8];
#pragma unroll
      for (int e = 0; e < 8; ++e) vv[e] = bfb2f(hv[e]);
      float s = 0.f, q = 0.f;
#pragma unroll
      for (int e = 0; e < 8; ++e) { s += vv[e]; q += vv[e]*vv[e]; }
      float mu = s * 0.125f;
      float var = q * 0.125f - mu * mu;
      float inv = rsqrtf(fmaxf(var, 0.0f) + 1e-5f);
      unsigned short o[8];
#pragma unroll
      for (int e = 0; e < 8; ++e) {
        float t = (vv[e] - mu) * inv * gmf[cb+e] + btf[cb+e];
        o[e] = f2bfb(fmaxf(t, 0.0f));
      }
      *(bf16x8*)p = *(bf16x8*)o;
    }
    asm volatile("" ::: "memory");
#pragma unroll
    for (int kt = 0; kt < KT1; ++kt) w1c[kt] = w1n[kt];
  }

  // ---- GEMM2: A-fragments to registers once; nt-outer with fused epilogue
  bf16x8 af0[KT2], af1[KT2];
#pragma unroll
  for (int kt = 0; kt < KT2; ++kt) {
    af0[kt] = *(const bf16x8*)&msgB[(w*32 + cl)      * SB + kt*32 + quad*8];
    af1[kt] = *(const bf16x8*)&msgB[(w*32 + 16 + cl) * SB + kt*32 + quad*8];
  }
  bf16x8 w2c[KT2], w2n[KT2];
#pragma unroll
  for (int kt = 0; kt < KT2; ++kt)
    w2c[kt] = *(const bf16x8*)&WbT[(size_t)cl * CMID + kt*32 + quad*8];
#pragma unroll
  for (int nt = 0; nt < NT; ++nt) {
    if (nt + 1 < NT) {
#pragma unroll
      for (int kt = 0; kt < KT2; ++kt)
        w2n[kt] = *(const bf16x8*)&WbT[(size_t)((nt+1)*16 + cl) * CMID + kt*32 + quad*8];
    }
    f32x4 a2[2];
    a2[0] = (f32x4){0.f, 0.f, 0.f, 0.f};
    a2[1] = (f32x4){0.f, 0.f, 0.f, 0.f};
#pragma unroll
    for (int kt = 0; kt < KT2; ++kt) {
      a2[0] = __builtin_amdgcn_mfma_f32_16x16x32_bf16(af0[kt], w2c[kt], a2[0], 0, 0, 0);
      a2[1] = __builtin_amdgcn_mfma_f32_16x16x32_bf16(af1[kt], w2c[kt], a2[1], 0, 0, 0);
    }
#pragma unroll
    for (int mt = 0; mt < 2; ++mt) {
      int node = node0 + w*2 + mt;
      float m = fmaxf(fmaxf(a2[mt][0], a2[mt][1]),
                      fmaxf(a2[mt][2], a2[mt][3]));
      m = fmaxf(m, __shfl_xor(m, 16, 64));
      m = fmaxf(m, __shfl_xor(m, 32, 64));
      float v = fmaxf(m + bbf[nt*16 + cl], 0.0f);
      if (quad == 0) {
        size_t oi = (size_t)node * CMID + nt*16 + cl;
        if (xoutb) xoutb[oi] = f2bfb(v);
        stv(bout, out_off + oi, mode, v);
      }
    }
#pragma unroll
    for (int kt = 0; kt < KT2; ++kt) w2c[kt] = w2n[kt];
  }
}

// ---------------------------------------------------------------------------
extern "C" void kernel_launch(void* const* d_in, const int* in_sizes, int n_in,
                              void* d_out, int out_size, void* d_ws, size_t ws_size,
                              hipStream_t stream) {
  (void)n_in; (void)ws_size; (void)in_sizes;
  int n = out_size / 256;
  if (n <= 0 || (n & 255)) n = 16384;

  float* ws = (float*)d_ws;
  int*    flag    = (int*)ws;                                       // 16 ints (0=mode, 4..9=bbox atomics)
  float4* pos4    = (float4*)(ws + 16);                             // 4n
  float*  h0      = ws + 16 + (size_t)4*n;                          // 6n
  int*    nbr     = (int*)(ws + 16 + (size_t)10*n);                 // 16n
  unsigned short* h1b = (unsigned short*)(ws + 16 + (size_t)26*n);  // 32n
  unsigned short* h2b = (unsigned short*)(ws + 16 + (size_t)58*n);  // 32n
  float*  vbuf    = ws + 16 + (size_t)90*n;                         // 1024
  unsigned short* wtbuf = (unsigned short*)(vbuf + 1024);           // 45056 shorts

  // grid-knn buffers (after wtbuf = 22528 floats)
  float* gbase = vbuf + 1024 + 22528;
  int*    cid       = (int*)gbase;            // n
  int*    counts    = cid + n;                // 32768
  int*    cellstart = counts + GR3;           // 32769 (padded to 32772)
  int*    cursor    = cellstart + 32772;      // 32769 (padded to 32772)
  int*    sidx      = cursor + 32772;         // n
  float4* spos4     = (float4*)(sidx + n);    // 4n floats (16B aligned)

  const int vsz[12] = {64,64,64,64, 64,64,64,64, 128,128,128,128};
  const int vsrc[12] = {3,4,5,7, 9,10,11,13, 15,16,17,19};
  CvtArgs ca;
  float* vptr[12];
  {
    int off = 0;
    for (int t = 0; t < 12; ++t) {
      ca.e[t].src = d_in[vsrc[t]];
      ca.e[t].dst = vbuf + off;
      ca.e[t].n   = vsz[t];
      vptr[t] = vbuf + off;
      off += vsz[t];
    }
  }
  const int wK[6]    = {9, 64, 67, 64, 67, 128};
  const int wN[6]    = {64, 64, 64, 64, 128, 128};
  const int wKp[6]   = {32, 64, 96, 64, 96, 128};
  const int wsrc[6]  = {2, 6, 8, 12, 14, 18};
  WArgs wa;
  unsigned short* wptr[6];
  {
    int off = 0;
    for (int t = 0; t < 6; ++t) {
      wa.e[t].src  = d_in[wsrc[t]];
      wa.e[t].dst  = wtbuf + off;
      wa.e[t].K    = wK[t];
      wa.e[t].N    = wN[t];
      wa.e[t].Kpad = wKp[t];
      wptr[t] = wtbuf + off;
      off += wN[t] * wKp[t];
    }
  }

  // ONE memset: all six bbox slots init to 0xFF (max stored as benc(-x))
  u32* bbx = (u32*)ws + 4;
  hipMemsetAsync(bbx, 0xFF, 24, stream);

  setup_kernel<<<n/256 + 7 + GR3/256, 256, 0, stream>>>(
      d_in[0], d_in[1], wa, ca, flag, pos4, h0, counts, n);

  hist_kernel<<<n/256, 256, 0, stream>>>(pos4, bbx, counts, cid, n);
  scan_kernel<<<1, 1024, 0, stream>>>(counts, cellstart, cursor);
  scatter_kernel<<<n/256, 256, 0, stream>>>(pos4, cid, cursor, sidx, spos4, n);
  knn7_kernel<<<n/KNN7_WPB, 256, 0, stream>>>(spos4, sidx, cellstart,
                                              bbx, nbr, n);

  // <CIN, CMID, KT1, NT, KT2>
  conv_mfma7_kernel<6, 64, 1, 4, 2><<<n/8, 256, 0, stream>>>(
      h0, (const unsigned short*)nullptr, pos4, nbr, flag, wptr[0], wptr[1],
      vptr[0], vptr[1], vptr[2], vptr[3], h1b, d_out, (size_t)0);
  conv_mfma7_kernel<64, 64, 3, 4, 2><<<n/8, 256, 0, stream>>>(
      (const float*)nullptr, h1b, pos4, nbr, flag, wptr[2], wptr[3],
      vptr[4], vptr[5], vptr[6], vptr[7], h2b, d_out, (size_t)n*64);
  conv_mfma7_kernel<64, 128, 3, 8, 4><<<n/8, 256, 0, stream>>>(
      (const float*)nullptr, h2b, pos4, nbr, flag, wptr[4], wptr[5],
      vptr[8], vptr[9], vptr[10], vptr[11],
      (unsigned short*)nullptr, d_out, (size_t)n*128);
}